// Round 2
// baseline (370.527 us; speedup 1.0000x reference)
//
#include <hip/hip_runtime.h>
#include <hip/hip_bf16.h>

// HorizonTemporalSelfAttention: multi-scale deformable attention
// bs=2, nq=16384, E=256, NH=8, NL=4, NP=4, d=32, total tokens=21760
//
// R7: logits stored as per-(b,h,q) 48-half records [32 off | 16 attn].
// R8: XCD-aware sampler swizzle (FETCH 126->43 MB; taps L2-resident).
// R9: sampler restructured to 1 thread = 1 query x all 32 channels.
//     R8 profile was latency-bound (VALU 44%, HBM 12%, VGPR=40 -> only ~4
//     tap loads in flight, coord/weight math duplicated 4x across c4 lanes).
//     Now: weight pipeline computed once per query, 16 independent 16B tap
//     loads issued per point (forced MLP), grid 2048x128 keeps XCD pinning.

typedef __attribute__((ext_vector_type(4))) float    float4v;
typedef __attribute__((ext_vector_type(8))) _Float16 half8;
typedef __attribute__((ext_vector_type(4))) _Float16 half4;
typedef __attribute__((ext_vector_type(2))) _Float16 half2v;

#define NQ    16384
#define NTOK  21760
#define LREC  48          // halves per (b,h,q) logit record: 32 off + 16 attn

#define GEMM_BLOCKS 768   // 256 M-tiles x 3 N-tiles
#define CONV_BLOCKS 10880 // 2785280 float4 / 256

union H8 { half8 v; half2v p[4]; };

// ---------------- K-F: fused GEMM + value convert ----------------
#define LDSTR 88
__global__ __launch_bounds__(256) void fused_kernel(
    const float* __restrict__ qf,
    const float* __restrict__ Woff, const float* __restrict__ Wattn,
    const float* __restrict__ boff, const float* __restrict__ battn,
    const float* __restrict__ val,
    _Float16* __restrict__ lh, _Float16* __restrict__ vh) {
  const int tid = threadIdx.x;

  if (blockIdx.x >= GEMM_BLOCKS) {
    // ---- value convert: f32 -> f16, one float4 per thread ----
    int i = (blockIdx.x - GEMM_BLOCKS) * 256 + tid;
    float4v v = ((const float4v*)val)[i];
    half4 o;
    o[0] = (_Float16)v[0]; o[1] = (_Float16)v[1];
    o[2] = (_Float16)v[2]; o[3] = (_Float16)v[3];
    ((half4*)vh)[i] = o;
    return;
  }

  // ---- GEMM: logits = q @ Wcat^T + bias -> per-(b,h,q) records ----
  __shared__ _Float16 As[128 * LDSTR];
  __shared__ _Float16 Bs[128 * LDSTR];

  const int lane = tid & 63;
  const int wv   = tid >> 6;
  const int wm   = wv >> 1, wn = wv & 1;
  const int quad = lane >> 4;
  const int r    = lane & 15;
  const int blockM = (blockIdx.x & 255) * 128;
  const int n0     = (blockIdx.x >> 8) * 128;

  float4v acc[4][4];
#pragma unroll
  for (int i = 0; i < 4; ++i)
#pragma unroll
    for (int j = 0; j < 4; ++j) acc[i][j] = (float4v){0.f, 0.f, 0.f, 0.f};

  for (int kc = 0; kc < 4; ++kc) {
    const int k0 = kc * 64;
    if (kc) __syncthreads();
    // A: 128 rows x 16 float4 k-cols, f32 -> f16
#pragma unroll
    for (int it = 0; it < 8; ++it) {
      int idx = it * 256 + tid;
      int row = idx >> 4, k4 = idx & 15;
      float4v v = *(const float4v*)(qf + (size_t)(blockM + row) * 256 + k0 + k4 * 4);
      half4 o;
      o[0] = (_Float16)v[0]; o[1] = (_Float16)v[1];
      o[2] = (_Float16)v[2]; o[3] = (_Float16)v[3];
      *(half4*)&As[row * LDSTR + k4 * 4] = o;
    }
    // B: 128 rows x 16 float4 k-cols from Wcat f32 (L2-resident, 394 KB)
#pragma unroll
    for (int it = 0; it < 8; ++it) {
      int idx = it * 256 + tid;
      int row = idx >> 4, k4 = idx & 15;
      int n = n0 + row;
      const float* src = (n < 256) ? (Woff + (size_t)n * 256)
                                   : (Wattn + (size_t)(n - 256) * 256);
      float4v v = *(const float4v*)(src + k0 + k4 * 4);
      half4 o;
      o[0] = (_Float16)v[0]; o[1] = (_Float16)v[1];
      o[2] = (_Float16)v[2]; o[3] = (_Float16)v[3];
      *(half4*)&Bs[row * LDSTR + k4 * 4] = o;
    }
    __syncthreads();

#pragma unroll
    for (int kf = 0; kf < 2; ++kf) {
      const int ko = kf * 32 + quad * 8;
      half8 af[4], bf[4];
#pragma unroll
      for (int mi = 0; mi < 4; ++mi)
        af[mi] = *(const half8*)&As[(wm * 64 + mi * 16 + r) * LDSTR + ko];
#pragma unroll
      for (int ni = 0; ni < 4; ++ni)
        bf[ni] = *(const half8*)&Bs[(wn * 64 + ni * 16 + r) * LDSTR + ko];
#pragma unroll
      for (int mi = 0; mi < 4; ++mi)
#pragma unroll
        for (int ni = 0; ni < 4; ++ni)
          acc[mi][ni] = __builtin_amdgcn_mfma_f32_16x16x32_f16(af[mi], bf[ni], acc[mi][ni], 0, 0, 0);
    }
  }

  // epilogue: n -> (head, slot): n<256: h=n>>5, slot=n&31 (offsets)
  //                              n>=256: h=(n-256)>>4, slot=32+((n-256)&15)
#pragma unroll
  for (int mi = 0; mi < 4; ++mi) {
    const int mb = blockM + wm * 64 + mi * 16 + quad * 4;
#pragma unroll
    for (int ni = 0; ni < 4; ++ni) {
      const int n = n0 + wn * 64 + ni * 16 + r;
      const float bias = (n < 256) ? boff[n] : battn[n - 256];
      const int h    = (n < 256) ? (n >> 5) : ((n - 256) >> 4);
      const int slot = (n < 256) ? (n & 31) : (32 + ((n - 256) & 15));
#pragma unroll
      for (int reg = 0; reg < 4; ++reg) {
        const int bq = mb + reg;
        const int b = bq >> 14, q = bq & 16383;
        lh[((size_t)(b * 8 + h) * NQ + q) * LREC + slot] =
            (_Float16)(acc[mi][ni][reg] + bias);
      }
    }
  }
}

// ---------------- K-S: sampling (1 thread = 1 query, 32 channels) ----------------
// grid 2048 blocks x 128 threads; XCD-aware decode:
//   xcd = bid & 7, local = bid >> 3 (0..255)
//   hb  = xcd*2 + (local>>7)  -> 2 (b,h) value slices pinned per XCD L2
//   qt  = local & 127         -> 128 q-tiles of 128 queries
// Per point: 16 independent dwordx4 tap loads in flight (4 taps x 4 chunks).
__global__ __launch_bounds__(128) void sample_kernel(
    const _Float16* __restrict__ vh, const float* __restrict__ refp,
    const _Float16* __restrict__ lh, float* __restrict__ out) {
  const int bid   = blockIdx.x;
  const int xcd   = bid & 7;
  const int local = bid >> 3;
  const int hb    = xcd * 2 + (local >> 7);   // 0..15, == b*8+h
  const int qt    = local & 127;
  const int h     = hb & 7;
  const int b     = hb >> 3;
  const int tid   = threadIdx.x;              // query within tile
  const int q     = qt * 128 + tid;
  const size_t bq = (size_t)b * NQ + q;
  const _Float16* rec = lh + ((size_t)hb * NQ + q) * LREC;

  // offsets: slots 0..31 kept as halves, converted on use (layout l*8+p*2+xy)
  half8 oh[4];
#pragma unroll
  for (int i = 0; i < 4; ++i) oh[i] = *(const half8*)(rec + i * 8);

  // attn logits: slots 32..47 -> softmax (f32), inv folded in
  float al[16];
#pragma unroll
  for (int i = 0; i < 2; ++i) {
    half8 ah = *(const half8*)(rec + 32 + i * 8);
#pragma unroll
    for (int j = 0; j < 8; ++j) al[i * 8 + j] = (float)ah[j];
  }
  float mx = -1e30f;
#pragma unroll
  for (int i = 0; i < 16; ++i) mx = fmaxf(mx, al[i]);
  float ssum = 0.f;
#pragma unroll
  for (int i = 0; i < 16; ++i) {
    float e = __expf(al[i] - mx);
    al[i] = e;
    ssum += e;
  }
  const float inv = 1.0f / ssum;
#pragma unroll
  for (int i = 0; i < 16; ++i) al[i] *= inv;

  float4v rp0 = *(const float4v*)(refp + bq * 8);
  float4v rp1 = *(const float4v*)(refp + bq * 8 + 4);
  const float rpx[4] = {rp0[0], rp0[2], rp1[0], rp1[2]};
  const float rpy[4] = {rp0[1], rp0[3], rp1[1], rp1[3]};

  const _Float16* vb = vh + (size_t)b * NTOK * 256 + h * 32;

  float accf[32];
#pragma unroll
  for (int i = 0; i < 32; ++i) accf[i] = 0.f;

  const int base[4] = {0, 16384, 20480, 21504};

#pragma unroll
  for (int l = 0; l < 4; ++l) {
    const int   W  = 128 >> l;
    const float fW = (float)W;
    const _Float16* vlev = vb + (size_t)base[l] * 256;
    half2v accl[16];
#pragma unroll
    for (int j = 0; j < 16; ++j) accl[j] = (half2v){(_Float16)0, (_Float16)0};
#pragma unroll
    for (int p = 0; p < 4; ++p) {
      const float a  = al[l * 4 + p];
      const float ox = (float)oh[l][p * 2];
      const float oy = (float)oh[l][p * 2 + 1];
      // (ref + off/shape)*2-1 through grid_sample == ref*W + off - 0.5
      const float x = rpx[p] * fW + ox - 0.5f;
      const float y = rpy[p] * fW + oy - 0.5f;
      const float xf = floorf(x), yf = floorf(y);
      const float fx = x - xf, fy = y - yf;
      const int ix = (int)xf, iy = (int)yf;
      const int ix0 = min(max(ix, 0), W - 1);
      const int ix1 = min(max(ix + 1, 0), W - 1);
      const int iy0 = min(max(iy, 0), W - 1);
      const int iy1 = min(max(iy + 1, 0), W - 1);
      const float wx0 = ((unsigned)ix       < (unsigned)W) ? 1.f - fx : 0.f;
      const float wx1 = ((unsigned)(ix + 1) < (unsigned)W) ? fx       : 0.f;
      const float wy0 = ((unsigned)iy       < (unsigned)W) ? 1.f - fy : 0.f;
      const float wy1 = ((unsigned)(iy + 1) < (unsigned)W) ? fy       : 0.f;
      const _Float16 w00 = (_Float16)(a * wx0 * wy0);
      const _Float16 w01 = (_Float16)(a * wx1 * wy0);
      const _Float16 w10 = (_Float16)(a * wx0 * wy1);
      const _Float16 w11 = (_Float16)(a * wx1 * wy1);
      const half2v h00 = (half2v){w00, w00};
      const half2v h01 = (half2v){w01, w01};
      const half2v h10 = (half2v){w10, w10};
      const half2v h11 = (half2v){w11, w11};
      const _Float16* p00 = vlev + (size_t)(iy0 * W + ix0) * 256;
      const _Float16* p01 = vlev + (size_t)(iy0 * W + ix1) * 256;
      const _Float16* p10 = vlev + (size_t)(iy1 * W + ix0) * 256;
      const _Float16* p11 = vlev + (size_t)(iy1 * W + ix1) * 256;
      // 16 independent 16B loads -- issue all before consuming
      H8 t00[4], t01[4], t10[4], t11[4];
#pragma unroll
      for (int j = 0; j < 4; ++j) {
        t00[j].v = *(const half8*)(p00 + j * 8);
        t01[j].v = *(const half8*)(p01 + j * 8);
        t10[j].v = *(const half8*)(p10 + j * 8);
        t11[j].v = *(const half8*)(p11 + j * 8);
      }
#pragma unroll
      for (int j = 0; j < 4; ++j)
#pragma unroll
        for (int k = 0; k < 4; ++k)
          accl[j * 4 + k] += h00 * t00[j].p[k] + h01 * t01[j].p[k]
                           + h10 * t10[j].p[k] + h11 * t11[j].p[k];
    }
    // flush level accumulator to f32 (channel ch = j*8 + k*2 (+1))
#pragma unroll
    for (int j = 0; j < 4; ++j)
#pragma unroll
      for (int k = 0; k < 4; ++k) {
        accf[j * 8 + k * 2]     += (float)accl[j * 4 + k][0];
        accf[j * 8 + k * 2 + 1] += (float)accl[j * 4 + k][1];
      }
  }

  // LDS transpose -> coalesced out[b][h*32+c][q]
  __shared__ float sm[32][129];
#pragma unroll
  for (int c = 0; c < 32; ++c) sm[c][tid] = accf[c];
  __syncthreads();
  const size_t obase = ((size_t)b * 256 + h * 32) * NQ + qt * 128;
#pragma unroll
  for (int i = 0; i < 32; ++i) {
    const int idx = i * 128 + tid;
    const int c = idx >> 7, qq = idx & 127;
    out[obase + (size_t)c * NQ + qq] = sm[c][qq];
  }
}

extern "C" void kernel_launch(void* const* d_in, const int* in_sizes, int n_in,
                              void* d_out, int out_size, void* d_ws, size_t ws_size,
                              hipStream_t stream) {
  const float* query = (const float*)d_in[0];
  const float* value = (const float*)d_in[1];
  const float* refp  = (const float*)d_in[2];
  const float* Woff  = (const float*)d_in[3];
  const float* boff  = (const float*)d_in[4];
  const float* Wattn = (const float*)d_in[5];
  const float* battn = (const float*)d_in[6];
  float* out = (float*)d_out;

  char* ws = (char*)d_ws;
  _Float16* vh = (_Float16*)ws;                    // 22,282,240 B
  _Float16* lh = (_Float16*)(ws + 22282240);       // 25,165,824 B

  fused_kernel<<<GEMM_BLOCKS + CONV_BLOCKS, 256, 0, stream>>>(
      query, Woff, Wattn, boff, battn, value, lh, vh);
  sample_kernel<<<2048, 128, 0, stream>>>(vh, refp, lh, out);
}

// Round 5
// 215.159 us; speedup vs baseline: 1.7221x; 1.7221x over previous
//
#include <hip/hip_runtime.h>
#include <hip/hip_bf16.h>

// HorizonTemporalSelfAttention: multi-scale deformable attention
// bs=2, nq=16384, E=256, NH=8, NL=4, NP=4, d=32, total tokens=21760
//
// R7: logits stored as per-(b,h,q) 48-half records [32 off | 16 attn].
// R8: XCD-aware sampler swizzle (FETCH 126->43 MB; taps L2-resident).
// R9 (REVERTED): 1-thread-per-query broke intra-line coalescing (4x L2
//     transactions, 239 us). Lesson: keep 4 lanes x 16B = one 64B segment
//     per tap in ONE instruction.
// R10/R11: R8 mapping + explicit 1-deep tap pipeline (container + macro
//     token-paste failures; never measured).
// R12: R10 with the paste fixed: (t##X##0).v -- `0.v` lexes as one
//     pp-number so it must not abut the paste. Semantics identical to R10.

typedef __attribute__((ext_vector_type(4))) float    float4v;
typedef __attribute__((ext_vector_type(8))) _Float16 half8;
typedef __attribute__((ext_vector_type(4))) _Float16 half4;
typedef __attribute__((ext_vector_type(2))) _Float16 half2v;

#define NQ    16384
#define NTOK  21760
#define LREC  48          // halves per (b,h,q) logit record: 32 off + 16 attn

#define GEMM_BLOCKS 768   // 256 M-tiles x 3 N-tiles
#define CONV_BLOCKS 10880 // 2785280 float4 / 256

union H8 { half8 v; half2v p[4]; };

// ---------------- K-F: fused GEMM + value convert ----------------
#define LDSTR 88
__global__ __launch_bounds__(256) void fused_kernel(
    const float* __restrict__ qf,
    const float* __restrict__ Woff, const float* __restrict__ Wattn,
    const float* __restrict__ boff, const float* __restrict__ battn,
    const float* __restrict__ val,
    _Float16* __restrict__ lh, _Float16* __restrict__ vh) {
  const int tid = threadIdx.x;

  if (blockIdx.x >= GEMM_BLOCKS) {
    // ---- value convert: f32 -> f16, one float4 per thread ----
    int i = (blockIdx.x - GEMM_BLOCKS) * 256 + tid;
    float4v v = ((const float4v*)val)[i];
    half4 o;
    o[0] = (_Float16)v[0]; o[1] = (_Float16)v[1];
    o[2] = (_Float16)v[2]; o[3] = (_Float16)v[3];
    ((half4*)vh)[i] = o;
    return;
  }

  // ---- GEMM: logits = q @ Wcat^T + bias -> per-(b,h,q) records ----
  __shared__ _Float16 As[128 * LDSTR];
  __shared__ _Float16 Bs[128 * LDSTR];

  const int lane = tid & 63;
  const int wv   = tid >> 6;
  const int wm   = wv >> 1, wn = wv & 1;
  const int quad = lane >> 4;
  const int r    = lane & 15;
  const int blockM = (blockIdx.x & 255) * 128;
  const int n0     = (blockIdx.x >> 8) * 128;

  float4v acc[4][4];
#pragma unroll
  for (int i = 0; i < 4; ++i)
#pragma unroll
    for (int j = 0; j < 4; ++j) acc[i][j] = (float4v){0.f, 0.f, 0.f, 0.f};

  for (int kc = 0; kc < 4; ++kc) {
    const int k0 = kc * 64;
    if (kc) __syncthreads();
    // A: 128 rows x 16 float4 k-cols, f32 -> f16
#pragma unroll
    for (int it = 0; it < 8; ++it) {
      int idx = it * 256 + tid;
      int row = idx >> 4, k4 = idx & 15;
      float4v v = *(const float4v*)(qf + (size_t)(blockM + row) * 256 + k0 + k4 * 4);
      half4 o;
      o[0] = (_Float16)v[0]; o[1] = (_Float16)v[1];
      o[2] = (_Float16)v[2]; o[3] = (_Float16)v[3];
      *(half4*)&As[row * LDSTR + k4 * 4] = o;
    }
    // B: 128 rows x 16 float4 k-cols from Wcat f32 (L2-resident, 394 KB)
#pragma unroll
    for (int it = 0; it < 8; ++it) {
      int idx = it * 256 + tid;
      int row = idx >> 4, k4 = idx & 15;
      int n = n0 + row;
      const float* src = (n < 256) ? (Woff + (size_t)n * 256)
                                   : (Wattn + (size_t)(n - 256) * 256);
      float4v v = *(const float4v*)(src + k0 + k4 * 4);
      half4 o;
      o[0] = (_Float16)v[0]; o[1] = (_Float16)v[1];
      o[2] = (_Float16)v[2]; o[3] = (_Float16)v[3];
      *(half4*)&Bs[row * LDSTR + k4 * 4] = o;
    }
    __syncthreads();

#pragma unroll
    for (int kf = 0; kf < 2; ++kf) {
      const int ko = kf * 32 + quad * 8;
      half8 af[4], bf[4];
#pragma unroll
      for (int mi = 0; mi < 4; ++mi)
        af[mi] = *(const half8*)&As[(wm * 64 + mi * 16 + r) * LDSTR + ko];
#pragma unroll
      for (int ni = 0; ni < 4; ++ni)
        bf[ni] = *(const half8*)&Bs[(wn * 64 + ni * 16 + r) * LDSTR + ko];
#pragma unroll
      for (int mi = 0; mi < 4; ++mi)
#pragma unroll
        for (int ni = 0; ni < 4; ++ni)
          acc[mi][ni] = __builtin_amdgcn_mfma_f32_16x16x32_f16(af[mi], bf[ni], acc[mi][ni], 0, 0, 0);
    }
  }

  // epilogue: n -> (head, slot): n<256: h=n>>5, slot=n&31 (offsets)
  //                              n>=256: h=(n-256)>>4, slot=32+((n-256)&15)
#pragma unroll
  for (int mi = 0; mi < 4; ++mi) {
    const int mb = blockM + wm * 64 + mi * 16 + quad * 4;
#pragma unroll
    for (int ni = 0; ni < 4; ++ni) {
      const int n = n0 + wn * 64 + ni * 16 + r;
      const float bias = (n < 256) ? boff[n] : battn[n - 256];
      const int h    = (n < 256) ? (n >> 5) : ((n - 256) >> 4);
      const int slot = (n < 256) ? (n & 31) : (32 + ((n - 256) & 15));
#pragma unroll
      for (int reg = 0; reg < 4; ++reg) {
        const int bq = mb + reg;
        const int b = bq >> 14, q = bq & 16383;
        lh[((size_t)(b * 8 + h) * NQ + q) * LREC + slot] =
            (_Float16)(acc[mi][ni][reg] + bias);
      }
    }
  }
}

// ---------------- K-S: sampling (R8 mapping + 1-deep tap pipeline) ----------------
// grid 4096 flat; xcd = bid&7, local = bid>>3, hb = xcd*2 + (local>>8),
// qt = local&255. thread: c4 = tid&3 (channels c4*8..+7), qi = tid>>2.
__global__ __launch_bounds__(256, 4) void sample_kernel(
    const _Float16* __restrict__ vh, const float* __restrict__ refp,
    const _Float16* __restrict__ lh, float* __restrict__ out) {
  const int bid   = blockIdx.x;
  const int xcd   = bid & 7;
  const int local = bid >> 3;
  const int hb    = xcd * 2 + (local >> 8);   // 0..15, == b*8+h
  const int qt    = local & 255;
  const int h     = hb & 7;
  const int b     = hb >> 3;
  const int tid = threadIdx.x;
  const int c4 = tid & 3;
  const int qi = tid >> 2;
  const int q  = qt * 64 + qi;
  const size_t bq = (size_t)b * NQ + q;
  const _Float16* rec = lh + ((size_t)hb * NQ + q) * LREC;

  // offsets: slots 0..31 kept as halves (half->float conversion is exact)
  half8 oh[4];
#pragma unroll
  for (int i = 0; i < 4; ++i) oh[i] = *(const half8*)(rec + i * 8);

  // attn logits: slots 32..47 -> softmax (f32), inv folded in (same rounding
  // as R8's per-use al[i]*inv)
  float al[16];
#pragma unroll
  for (int i = 0; i < 2; ++i) {
    half8 ah = *(const half8*)(rec + 32 + i * 8);
#pragma unroll
    for (int j = 0; j < 8; ++j) al[i * 8 + j] = (float)ah[j];
  }
  float mx = -1e30f;
#pragma unroll
  for (int i = 0; i < 16; ++i) mx = fmaxf(mx, al[i]);
  float ssum = 0.f;
#pragma unroll
  for (int i = 0; i < 16; ++i) {
    float e = __expf(al[i] - mx);
    al[i] = e;
    ssum += e;
  }
  const float inv = 1.0f / ssum;
#pragma unroll
  for (int i = 0; i < 16; ++i) al[i] *= inv;

  float4v rp0 = *(const float4v*)(refp + bq * 8);
  float4v rp1 = *(const float4v*)(refp + bq * 8 + 4);
  const float rpx[4] = {rp0[0], rp0[2], rp1[0], rp1[2]};
  const float rpy[4] = {rp0[1], rp0[3], rp1[1], rp1[3]};

  const _Float16* vb = vh + (size_t)b * NTOK * 256 + h * 32 + c4 * 8;

  float4v acc0 = (float4v){0.f, 0.f, 0.f, 0.f};
  float4v acc1 = (float4v){0.f, 0.f, 0.f, 0.f};
  half2v accl0 = (half2v){(_Float16)0, (_Float16)0};
  half2v accl1 = (half2v){(_Float16)0, (_Float16)0};
  half2v accl2 = (half2v){(_Float16)0, (_Float16)0};
  half2v accl3 = (half2v){(_Float16)0, (_Float16)0};

  // named double buffers (no runtime-indexed arrays -> no scratch)
  H8 tA0, tA1, tA2, tA3, tB0, tB1, tB2, tB3;
  half2v wA0, wA1, wA2, wA3, wB0, wB1, wB2, wB3;

  // STAGE(K, X): compute addr+weights for flat point K = l*4+p, issue the
  // 4 tap loads into buffer X. Weight/coord formulas identical to R8.
  // NOTE: pasted identifiers are parenthesized before member access --
  // `t##X##0.v` would lex `0.v` as one pp-number and break the paste.
#define STAGE(K, X) {                                                        \
    const int l_ = (K) >> 2, p_ = (K) & 3;                                   \
    const int W_ = 128 >> l_;                                                \
    const int base_ = (l_ == 0) ? 0 : (l_ == 1) ? 16384                      \
                     : (l_ == 2) ? 20480 : 21504;                            \
    const float fW_ = (float)W_;                                             \
    const float a_  = al[K];                                                 \
    const float ox_ = (float)oh[l_][p_ * 2];                                 \
    const float oy_ = (float)oh[l_][p_ * 2 + 1];                             \
    const float x_ = rpx[p_] * fW_ + ox_ - 0.5f;                             \
    const float y_ = rpy[p_] * fW_ + oy_ - 0.5f;                             \
    const float xf_ = floorf(x_), yf_ = floorf(y_);                          \
    const float fx_ = x_ - xf_, fy_ = y_ - yf_;                              \
    const int ix_ = (int)xf_, iy_ = (int)yf_;                                \
    const int ix0_ = min(max(ix_, 0), W_ - 1);                               \
    const int ix1_ = min(max(ix_ + 1, 0), W_ - 1);                           \
    const int iy0_ = min(max(iy_, 0), W_ - 1);                               \
    const int iy1_ = min(max(iy_ + 1, 0), W_ - 1);                           \
    const float wx0_ = ((unsigned)ix_       < (unsigned)W_) ? 1.f - fx_ : 0.f; \
    const float wx1_ = ((unsigned)(ix_ + 1) < (unsigned)W_) ? fx_       : 0.f; \
    const float wy0_ = ((unsigned)iy_       < (unsigned)W_) ? 1.f - fy_ : 0.f; \
    const float wy1_ = ((unsigned)(iy_ + 1) < (unsigned)W_) ? fy_       : 0.f; \
    const _Float16 w00_ = (_Float16)(a_ * wx0_ * wy0_);                      \
    const _Float16 w01_ = (_Float16)(a_ * wx1_ * wy0_);                      \
    const _Float16 w10_ = (_Float16)(a_ * wx0_ * wy1_);                      \
    const _Float16 w11_ = (_Float16)(a_ * wx1_ * wy1_);                      \
    w##X##0 = (half2v){w00_, w00_};                                          \
    w##X##1 = (half2v){w01_, w01_};                                          \
    w##X##2 = (half2v){w10_, w10_};                                          \
    w##X##3 = (half2v){w11_, w11_};                                          \
    const _Float16* vlev_ = vb + (size_t)base_ * 256;                        \
    const _Float16* r0_ = vlev_ + (size_t)(iy0_ * W_) * 256;                 \
    const _Float16* r1_ = vlev_ + (size_t)(iy1_ * W_) * 256;                 \
    (t##X##0).v = *(const half8*)(r0_ + ix0_ * 256);                         \
    (t##X##1).v = *(const half8*)(r0_ + ix1_ * 256);                         \
    (t##X##2).v = *(const half8*)(r1_ + ix0_ * 256);                         \
    (t##X##3).v = *(const half8*)(r1_ + ix1_ * 256);                         \
  }

  // CONSUME(X): blend buffer X into the level accumulator (same expression
  // order as R8: ((w00*t00 + w01*t01) + w10*t10) + w11*t11, j = 0..3)
#define CONSUME(X) {                                                         \
    accl0 += w##X##0 * (t##X##0).p[0] + w##X##1 * (t##X##1).p[0]             \
           + w##X##2 * (t##X##2).p[0] + w##X##3 * (t##X##3).p[0];            \
    accl1 += w##X##0 * (t##X##0).p[1] + w##X##1 * (t##X##1).p[1]             \
           + w##X##2 * (t##X##2).p[1] + w##X##3 * (t##X##3).p[1];            \
    accl2 += w##X##0 * (t##X##0).p[2] + w##X##1 * (t##X##1).p[2]             \
           + w##X##2 * (t##X##2).p[2] + w##X##3 * (t##X##3).p[2];            \
    accl3 += w##X##0 * (t##X##0).p[3] + w##X##1 * (t##X##1).p[3]             \
           + w##X##2 * (t##X##2).p[3] + w##X##3 * (t##X##3).p[3];            \
  }

  // FLUSH: level accumulator -> f32, reset (same order as R8)
#define FLUSH() {                                                            \
    acc0[0] += (float)accl0[0]; acc0[1] += (float)accl0[1];                  \
    acc0[2] += (float)accl1[0]; acc0[3] += (float)accl1[1];                  \
    acc1[0] += (float)accl2[0]; acc1[1] += (float)accl2[1];                  \
    acc1[2] += (float)accl3[0]; acc1[3] += (float)accl3[1];                  \
    accl0 = (half2v){(_Float16)0, (_Float16)0};                              \
    accl1 = (half2v){(_Float16)0, (_Float16)0};                              \
    accl2 = (half2v){(_Float16)0, (_Float16)0};                              \
    accl3 = (half2v){(_Float16)0, (_Float16)0};                              \
  }

  STAGE(0, A)
  STAGE(1, B)  CONSUME(A)
  STAGE(2, A)  CONSUME(B)
  STAGE(3, B)  CONSUME(A)
  STAGE(4, A)  CONSUME(B)  FLUSH()   // level 0 done
  STAGE(5, B)  CONSUME(A)
  STAGE(6, A)  CONSUME(B)
  STAGE(7, B)  CONSUME(A)
  STAGE(8, A)  CONSUME(B)  FLUSH()   // level 1 done
  STAGE(9, B)  CONSUME(A)
  STAGE(10, A) CONSUME(B)
  STAGE(11, B) CONSUME(A)
  STAGE(12, A) CONSUME(B)  FLUSH()   // level 2 done
  STAGE(13, B) CONSUME(A)
  STAGE(14, A) CONSUME(B)
  STAGE(15, B) CONSUME(A)
               CONSUME(B)  FLUSH()   // level 3 done
#undef STAGE
#undef CONSUME
#undef FLUSH

  // LDS transpose -> coalesced out[b][h*32+c][q]
  __shared__ float sm[32][65];
#pragma unroll
  for (int j = 0; j < 4; ++j) {
    sm[c4 * 8 + j][qi]     = acc0[j];
    sm[c4 * 8 + 4 + j][qi] = acc1[j];
  }
  __syncthreads();
  const size_t obase = ((size_t)b * 256 + h * 32) * NQ + qt * 64;
#pragma unroll
  for (int i = 0; i < 8; ++i) {
    const int idx = i * 256 + tid;
    const int c = idx >> 6, qq = idx & 63;
    out[obase + (size_t)c * NQ + qq] = sm[c][qq];
  }
}

extern "C" void kernel_launch(void* const* d_in, const int* in_sizes, int n_in,
                              void* d_out, int out_size, void* d_ws, size_t ws_size,
                              hipStream_t stream) {
  const float* query = (const float*)d_in[0];
  const float* value = (const float*)d_in[1];
  const float* refp  = (const float*)d_in[2];
  const float* Woff  = (const float*)d_in[3];
  const float* boff  = (const float*)d_in[4];
  const float* Wattn = (const float*)d_in[5];
  const float* battn = (const float*)d_in[6];
  float* out = (float*)d_out;

  char* ws = (char*)d_ws;
  _Float16* vh = (_Float16*)ws;                    // 22,282,240 B
  _Float16* lh = (_Float16*)(ws + 22282240);       // 25,165,824 B

  fused_kernel<<<GEMM_BLOCKS + CONV_BLOCKS, 256, 0, stream>>>(
      query, Woff, Wattn, boff, battn, value, lh, vh);
  sample_kernel<<<4096, 256, 0, stream>>>(vh, refp, lh, out);
}

// Round 6
// 211.666 us; speedup vs baseline: 1.7505x; 1.0165x over previous
//
#include <hip/hip_runtime.h>
#include <hip/hip_bf16.h>

// HorizonTemporalSelfAttention: multi-scale deformable attention
// bs=2, nq=16384, E=256, NH=8, NL=4, NP=4, d=32, total tokens=21760
//
// R7: logits stored as per-(b,h,q) 48-half records [32 off | 16 attn].
// R8: XCD-aware sampler swizzle (FETCH 126->43 MB; taps L2-resident).
// R9 (REVERTED): 1-thread-per-query broke intra-line coalescing (4x L2
//     transactions, 239 us). Lesson: keep 4 lanes x 16B = one 64B segment
//     per tap in ONE instruction.
// R12: 1-deep A/B tap pipeline: 79.7->76.4 us but VGPR only 52 -> allocator
//     sank loads, pipeline mostly defeated. Still latency-bound.
// R13: 4-deep A/B/C/D pipeline + launch_bounds(256,3) (VGPR cap ~168) so
//     the allocator can keep 3 points' taps (12 loads) in flight during
//     each consume (implicit counted-vmcnt). Numerics identical.

typedef __attribute__((ext_vector_type(4))) float    float4v;
typedef __attribute__((ext_vector_type(8))) _Float16 half8;
typedef __attribute__((ext_vector_type(4))) _Float16 half4;
typedef __attribute__((ext_vector_type(2))) _Float16 half2v;

#define NQ    16384
#define NTOK  21760
#define LREC  48          // halves per (b,h,q) logit record: 32 off + 16 attn

#define GEMM_BLOCKS 768   // 256 M-tiles x 3 N-tiles
#define CONV_BLOCKS 10880 // 2785280 float4 / 256

union H8 { half8 v; half2v p[4]; };

// ---------------- K-F: fused GEMM + value convert ----------------
#define LDSTR 88
__global__ __launch_bounds__(256) void fused_kernel(
    const float* __restrict__ qf,
    const float* __restrict__ Woff, const float* __restrict__ Wattn,
    const float* __restrict__ boff, const float* __restrict__ battn,
    const float* __restrict__ val,
    _Float16* __restrict__ lh, _Float16* __restrict__ vh) {
  const int tid = threadIdx.x;

  if (blockIdx.x >= GEMM_BLOCKS) {
    // ---- value convert: f32 -> f16, one float4 per thread ----
    int i = (blockIdx.x - GEMM_BLOCKS) * 256 + tid;
    float4v v = ((const float4v*)val)[i];
    half4 o;
    o[0] = (_Float16)v[0]; o[1] = (_Float16)v[1];
    o[2] = (_Float16)v[2]; o[3] = (_Float16)v[3];
    ((half4*)vh)[i] = o;
    return;
  }

  // ---- GEMM: logits = q @ Wcat^T + bias -> per-(b,h,q) records ----
  __shared__ _Float16 As[128 * LDSTR];
  __shared__ _Float16 Bs[128 * LDSTR];

  const int lane = tid & 63;
  const int wv   = tid >> 6;
  const int wm   = wv >> 1, wn = wv & 1;
  const int quad = lane >> 4;
  const int r    = lane & 15;
  const int blockM = (blockIdx.x & 255) * 128;
  const int n0     = (blockIdx.x >> 8) * 128;

  float4v acc[4][4];
#pragma unroll
  for (int i = 0; i < 4; ++i)
#pragma unroll
    for (int j = 0; j < 4; ++j) acc[i][j] = (float4v){0.f, 0.f, 0.f, 0.f};

  for (int kc = 0; kc < 4; ++kc) {
    const int k0 = kc * 64;
    if (kc) __syncthreads();
    // A: 128 rows x 16 float4 k-cols, f32 -> f16
#pragma unroll
    for (int it = 0; it < 8; ++it) {
      int idx = it * 256 + tid;
      int row = idx >> 4, k4 = idx & 15;
      float4v v = *(const float4v*)(qf + (size_t)(blockM + row) * 256 + k0 + k4 * 4);
      half4 o;
      o[0] = (_Float16)v[0]; o[1] = (_Float16)v[1];
      o[2] = (_Float16)v[2]; o[3] = (_Float16)v[3];
      *(half4*)&As[row * LDSTR + k4 * 4] = o;
    }
    // B: 128 rows x 16 float4 k-cols from Wcat f32 (L2-resident, 394 KB)
#pragma unroll
    for (int it = 0; it < 8; ++it) {
      int idx = it * 256 + tid;
      int row = idx >> 4, k4 = idx & 15;
      int n = n0 + row;
      const float* src = (n < 256) ? (Woff + (size_t)n * 256)
                                   : (Wattn + (size_t)(n - 256) * 256);
      float4v v = *(const float4v*)(src + k0 + k4 * 4);
      half4 o;
      o[0] = (_Float16)v[0]; o[1] = (_Float16)v[1];
      o[2] = (_Float16)v[2]; o[3] = (_Float16)v[3];
      *(half4*)&Bs[row * LDSTR + k4 * 4] = o;
    }
    __syncthreads();

#pragma unroll
    for (int kf = 0; kf < 2; ++kf) {
      const int ko = kf * 32 + quad * 8;
      half8 af[4], bf[4];
#pragma unroll
      for (int mi = 0; mi < 4; ++mi)
        af[mi] = *(const half8*)&As[(wm * 64 + mi * 16 + r) * LDSTR + ko];
#pragma unroll
      for (int ni = 0; ni < 4; ++ni)
        bf[ni] = *(const half8*)&Bs[(wn * 64 + ni * 16 + r) * LDSTR + ko];
#pragma unroll
      for (int mi = 0; mi < 4; ++mi)
#pragma unroll
        for (int ni = 0; ni < 4; ++ni)
          acc[mi][ni] = __builtin_amdgcn_mfma_f32_16x16x32_f16(af[mi], bf[ni], acc[mi][ni], 0, 0, 0);
    }
  }

  // epilogue: n -> (head, slot): n<256: h=n>>5, slot=n&31 (offsets)
  //                              n>=256: h=(n-256)>>4, slot=32+((n-256)&15)
#pragma unroll
  for (int mi = 0; mi < 4; ++mi) {
    const int mb = blockM + wm * 64 + mi * 16 + quad * 4;
#pragma unroll
    for (int ni = 0; ni < 4; ++ni) {
      const int n = n0 + wn * 64 + ni * 16 + r;
      const float bias = (n < 256) ? boff[n] : battn[n - 256];
      const int h    = (n < 256) ? (n >> 5) : ((n - 256) >> 4);
      const int slot = (n < 256) ? (n & 31) : (32 + ((n - 256) & 15));
#pragma unroll
      for (int reg = 0; reg < 4; ++reg) {
        const int bq = mb + reg;
        const int b = bq >> 14, q = bq & 16383;
        lh[((size_t)(b * 8 + h) * NQ + q) * LREC + slot] =
            (_Float16)(acc[mi][ni][reg] + bias);
      }
    }
  }
}

// ---------------- K-S: sampling (R8 mapping + 4-deep tap pipeline) ----------------
// grid 4096 flat; xcd = bid&7, local = bid>>3, hb = xcd*2 + (local>>8),
// qt = local&255. thread: c4 = tid&3 (channels c4*8..+7), qi = tid>>2.
__global__ __launch_bounds__(256, 3) void sample_kernel(
    const _Float16* __restrict__ vh, const float* __restrict__ refp,
    const _Float16* __restrict__ lh, float* __restrict__ out) {
  const int bid   = blockIdx.x;
  const int xcd   = bid & 7;
  const int local = bid >> 3;
  const int hb    = xcd * 2 + (local >> 8);   // 0..15, == b*8+h
  const int qt    = local & 255;
  const int h     = hb & 7;
  const int b     = hb >> 3;
  const int tid = threadIdx.x;
  const int c4 = tid & 3;
  const int qi = tid >> 2;
  const int q  = qt * 64 + qi;
  const size_t bq = (size_t)b * NQ + q;
  const _Float16* rec = lh + ((size_t)hb * NQ + q) * LREC;

  // offsets: slots 0..31 kept as halves (half->float conversion is exact)
  half8 oh[4];
#pragma unroll
  for (int i = 0; i < 4; ++i) oh[i] = *(const half8*)(rec + i * 8);

  // attn logits: slots 32..47 -> softmax (f32), inv folded in
  float al[16];
#pragma unroll
  for (int i = 0; i < 2; ++i) {
    half8 ah = *(const half8*)(rec + 32 + i * 8);
#pragma unroll
    for (int j = 0; j < 8; ++j) al[i * 8 + j] = (float)ah[j];
  }
  float mx = -1e30f;
#pragma unroll
  for (int i = 0; i < 16; ++i) mx = fmaxf(mx, al[i]);
  float ssum = 0.f;
#pragma unroll
  for (int i = 0; i < 16; ++i) {
    float e = __expf(al[i] - mx);
    al[i] = e;
    ssum += e;
  }
  const float inv = 1.0f / ssum;
#pragma unroll
  for (int i = 0; i < 16; ++i) al[i] *= inv;

  float4v rp0 = *(const float4v*)(refp + bq * 8);
  float4v rp1 = *(const float4v*)(refp + bq * 8 + 4);
  const float rpx[4] = {rp0[0], rp0[2], rp1[0], rp1[2]};
  const float rpy[4] = {rp0[1], rp0[3], rp1[1], rp1[3]};

  const _Float16* vb = vh + (size_t)b * NTOK * 256 + h * 32 + c4 * 8;

  float4v acc0 = (float4v){0.f, 0.f, 0.f, 0.f};
  float4v acc1 = (float4v){0.f, 0.f, 0.f, 0.f};
  half2v accl0 = (half2v){(_Float16)0, (_Float16)0};
  half2v accl1 = (half2v){(_Float16)0, (_Float16)0};
  half2v accl2 = (half2v){(_Float16)0, (_Float16)0};
  half2v accl3 = (half2v){(_Float16)0, (_Float16)0};

  // named 4-deep buffers (no runtime-indexed arrays -> no scratch)
  H8 tA0, tA1, tA2, tA3, tB0, tB1, tB2, tB3;
  H8 tC0, tC1, tC2, tC3, tD0, tD1, tD2, tD3;
  half2v wA0, wA1, wA2, wA3, wB0, wB1, wB2, wB3;
  half2v wC0, wC1, wC2, wC3, wD0, wD1, wD2, wD3;

  // STAGE(K, X): compute addr+weights for flat point K = l*4+p, issue the
  // 4 tap loads into buffer X. Weight/coord formulas identical to R8.
  // NOTE: pasted identifiers are parenthesized before member access --
  // `t##X##0.v` would lex `0.v` as one pp-number and break the paste.
#define STAGE(K, X) {                                                        \
    const int l_ = (K) >> 2, p_ = (K) & 3;                                   \
    const int W_ = 128 >> l_;                                                \
    const int base_ = (l_ == 0) ? 0 : (l_ == 1) ? 16384                      \
                     : (l_ == 2) ? 20480 : 21504;                            \
    const float fW_ = (float)W_;                                             \
    const float a_  = al[K];                                                 \
    const float ox_ = (float)oh[l_][p_ * 2];                                 \
    const float oy_ = (float)oh[l_][p_ * 2 + 1];                             \
    const float x_ = rpx[p_] * fW_ + ox_ - 0.5f;                             \
    const float y_ = rpy[p_] * fW_ + oy_ - 0.5f;                             \
    const float xf_ = floorf(x_), yf_ = floorf(y_);                          \
    const float fx_ = x_ - xf_, fy_ = y_ - yf_;                              \
    const int ix_ = (int)xf_, iy_ = (int)yf_;                                \
    const int ix0_ = min(max(ix_, 0), W_ - 1);                               \
    const int ix1_ = min(max(ix_ + 1, 0), W_ - 1);                           \
    const int iy0_ = min(max(iy_, 0), W_ - 1);                               \
    const int iy1_ = min(max(iy_ + 1, 0), W_ - 1);                           \
    const float wx0_ = ((unsigned)ix_       < (unsigned)W_) ? 1.f - fx_ : 0.f; \
    const float wx1_ = ((unsigned)(ix_ + 1) < (unsigned)W_) ? fx_       : 0.f; \
    const float wy0_ = ((unsigned)iy_       < (unsigned)W_) ? 1.f - fy_ : 0.f; \
    const float wy1_ = ((unsigned)(iy_ + 1) < (unsigned)W_) ? fy_       : 0.f; \
    const _Float16 w00_ = (_Float16)(a_ * wx0_ * wy0_);                      \
    const _Float16 w01_ = (_Float16)(a_ * wx1_ * wy0_);                      \
    const _Float16 w10_ = (_Float16)(a_ * wx0_ * wy1_);                      \
    const _Float16 w11_ = (_Float16)(a_ * wx1_ * wy1_);                      \
    w##X##0 = (half2v){w00_, w00_};                                          \
    w##X##1 = (half2v){w01_, w01_};                                          \
    w##X##2 = (half2v){w10_, w10_};                                          \
    w##X##3 = (half2v){w11_, w11_};                                          \
    const _Float16* vlev_ = vb + (size_t)base_ * 256;                        \
    const _Float16* r0_ = vlev_ + (size_t)(iy0_ * W_) * 256;                 \
    const _Float16* r1_ = vlev_ + (size_t)(iy1_ * W_) * 256;                 \
    (t##X##0).v = *(const half8*)(r0_ + ix0_ * 256);                         \
    (t##X##1).v = *(const half8*)(r0_ + ix1_ * 256);                         \
    (t##X##2).v = *(const half8*)(r1_ + ix0_ * 256);                         \
    (t##X##3).v = *(const half8*)(r1_ + ix1_ * 256);                         \
  }

  // CONSUME(X): blend buffer X into the level accumulator (same expression
  // order as R8: ((w00*t00 + w01*t01) + w10*t10) + w11*t11, j = 0..3)
#define CONSUME(X) {                                                         \
    accl0 += w##X##0 * (t##X##0).p[0] + w##X##1 * (t##X##1).p[0]             \
           + w##X##2 * (t##X##2).p[0] + w##X##3 * (t##X##3).p[0];            \
    accl1 += w##X##0 * (t##X##0).p[1] + w##X##1 * (t##X##1).p[1]             \
           + w##X##2 * (t##X##2).p[1] + w##X##3 * (t##X##3).p[1];            \
    accl2 += w##X##0 * (t##X##0).p[2] + w##X##1 * (t##X##1).p[2]             \
           + w##X##2 * (t##X##2).p[2] + w##X##3 * (t##X##3).p[2];            \
    accl3 += w##X##0 * (t##X##0).p[3] + w##X##1 * (t##X##1).p[3]             \
           + w##X##2 * (t##X##2).p[3] + w##X##3 * (t##X##3).p[3];            \
  }

  // FLUSH: level accumulator -> f32, reset (same order as R8)
#define FLUSH() {                                                            \
    acc0[0] += (float)accl0[0]; acc0[1] += (float)accl0[1];                  \
    acc0[2] += (float)accl1[0]; acc0[3] += (float)accl1[1];                  \
    acc1[0] += (float)accl2[0]; acc1[1] += (float)accl2[1];                  \
    acc1[2] += (float)accl3[0]; acc1[3] += (float)accl3[1];                  \
    accl0 = (half2v){(_Float16)0, (_Float16)0};                              \
    accl1 = (half2v){(_Float16)0, (_Float16)0};                              \
    accl2 = (half2v){(_Float16)0, (_Float16)0};                              \
    accl3 = (half2v){(_Float16)0, (_Float16)0};                              \
  }

  // 4-deep schedule: 3 younger points' loads (12) in flight per consume.
  STAGE(0, A)  STAGE(1, B)  STAGE(2, C)  STAGE(3, D)
  CONSUME(A)   STAGE(4, A)
  CONSUME(B)   STAGE(5, B)
  CONSUME(C)   STAGE(6, C)
  CONSUME(D)   FLUSH()      STAGE(7, D)   // level 0 done
  CONSUME(A)   STAGE(8, A)
  CONSUME(B)   STAGE(9, B)
  CONSUME(C)   STAGE(10, C)
  CONSUME(D)   FLUSH()      STAGE(11, D)  // level 1 done
  CONSUME(A)   STAGE(12, A)
  CONSUME(B)   STAGE(13, B)
  CONSUME(C)   STAGE(14, C)
  CONSUME(D)   FLUSH()      STAGE(15, D)  // level 2 done
  CONSUME(A)   CONSUME(B)   CONSUME(C)   CONSUME(D)  FLUSH()  // level 3 done
#undef STAGE
#undef CONSUME
#undef FLUSH

  // LDS transpose -> coalesced out[b][h*32+c][q]
  __shared__ float sm[32][65];
#pragma unroll
  for (int j = 0; j < 4; ++j) {
    sm[c4 * 8 + j][qi]     = acc0[j];
    sm[c4 * 8 + 4 + j][qi] = acc1[j];
  }
  __syncthreads();
  const size_t obase = ((size_t)b * 256 + h * 32) * NQ + qt * 64;
#pragma unroll
  for (int i = 0; i < 8; ++i) {
    const int idx = i * 256 + tid;
    const int c = idx >> 6, qq = idx & 63;
    out[obase + (size_t)c * NQ + qq] = sm[c][qq];
  }
}

extern "C" void kernel_launch(void* const* d_in, const int* in_sizes, int n_in,
                              void* d_out, int out_size, void* d_ws, size_t ws_size,
                              hipStream_t stream) {
  const float* query = (const float*)d_in[0];
  const float* value = (const float*)d_in[1];
  const float* refp  = (const float*)d_in[2];
  const float* Woff  = (const float*)d_in[3];
  const float* boff  = (const float*)d_in[4];
  const float* Wattn = (const float*)d_in[5];
  const float* battn = (const float*)d_in[6];
  float* out = (float*)d_out;

  char* ws = (char*)d_ws;
  _Float16* vh = (_Float16*)ws;                    // 22,282,240 B
  _Float16* lh = (_Float16*)(ws + 22282240);       // 25,165,824 B

  fused_kernel<<<GEMM_BLOCKS + CONV_BLOCKS, 256, 0, stream>>>(
      query, Woff, Wattn, boff, battn, value, lh, vh);
  sample_kernel<<<4096, 256, 0, stream>>>(vh, refp, lh, out);
}